// Round 9
// baseline (257.911 us; speedup 1.0000x reference)
//
#include <hip/hip_runtime.h>
#include <stdint.h>

// Disable FP contraction file-wide: the d2 <= R2 inclusion test is a discrete
// decision that must match the reference's fp32 mul+add rounding (XLA/numpy do
// not fuse into fma across ops).
#pragma clang fp contract(off)

#define S 256
#define NPTS 100000
#define BATCH 4
#define CCH 64
#define K 8
#define CAP 20   // per-pixel candidate list capacity (lambda<=3.4, P(>20)~1e-10)

static constexpr float R2 = 0.01171875f * 0.01171875f;  // (1.5/256*2)^2, exact
static constexpr unsigned long long SENT = 0xFFFFFFFFFFFFFFFFULL;

// ===========================================================================
// Stage 1 -- Scatter: 16 THREADS PER POINT (one per 4x4 cell), append-list
// commit. PROVEN (R1; ~15 us standalone). R2's 1-thread/point regressed
// +25 us: the 16-way split gives 16x more independent atomic+store chains
// per wave for latency hiding.
// key = (z_bits << 32) | point_idx -- ascending (z, idx) == reference
// lexsort rank; keys unique, so deferred selection reproduces the reference
// top-K exactly regardless of commit order.
// ===========================================================================
__global__ __launch_bounds__(256) void scatter_list_kernel(
        const float* __restrict__ pts,
        unsigned int* __restrict__ counts,
        unsigned long long* __restrict__ lists) {
    int gid = blockIdx.x * blockDim.x + threadIdx.x;
    if (gid >= BATCH * NPTS * 16) return;
    int cell = gid & 15;
    int pid  = gid >> 4;
    int b = pid / NPTS;
    int n = pid - b * NPTS;

    const float* p = pts + (size_t)pid * 3;
    float x = -p[0];                 // reference flips x,y signs
    float y = -p[1];
    float z = p[2];
    if (!(z >= 0.0f)) return;

    float px = (1.0f - x) * 128.0f - 0.5f;   // (1-x)*(S/2) - 0.5
    float py = (1.0f - y) * 128.0f - 0.5f;
    int cj0 = (int)floorf(px);
    int ci0 = (int)floorf(py);

    int ci = ci0 - 1 + (cell >> 2);
    int cj = cj0 - 1 + (cell & 3);
    if (ci < 0 || ci >= S || cj < 0 || cj >= S) return;

    float cy = 1.0f - 2.0f * ((float)ci + 0.5f) / 256.0f;
    float cx = 1.0f - 2.0f * ((float)cj + 0.5f) / 256.0f;
    float dy = cy - y;
    float dx = cx - x;
    float d2 = dy * dy + dx * dx;
    if (!(d2 <= R2)) return;

    unsigned long long key =
        ((unsigned long long)__float_as_uint(z) << 32) | (unsigned int)n;
    size_t base = (size_t)b * (S * S) + (size_t)(ci * S + cj);
    unsigned int old = atomicAdd(&counts[base], 1u);
    if (old < CAP) lists[base * CAP + old] = key;
}

// compare-swap (ascending) and sorted-insert for the streaming top-8.
// Inserting SENT is a no-op (SENT >= t7 always).
#define CSW(a, b) do {                                        \
        unsigned long long _lo = (a) < (b) ? (a) : (b);       \
        unsigned long long _hi = (a) < (b) ? (b) : (a);       \
        (a) = _lo; (b) = _hi;                                 \
    } while (0)
#define INSERT8(x) do {                                       \
        unsigned long long _x = (x);                          \
        t7 = t7 < _x ? t7 : _x;                               \
        CSW(t6, t7); CSW(t5, t6); CSW(t4, t5); CSW(t3, t4);   \
        CSW(t2, t3); CSW(t1, t2); CSW(t0, t1);                \
    } while (0)
// masked insert of pair j from named register q (branch-free: cndmask)
#define PAIR(j, q) do {                                                   \
        INSERT8((2 * (j)     < c) ? (q).x : SENT);                        \
        INSERT8((2 * (j) + 1 < c) ? (q).y : SENT);                        \
    } while (0)

// ===========================================================================
// Stage 2 -- Blend: ONE BLOCK = ONE FULL IMAGE ROW (256 pixels), 1024 blocks.
//
// R6 POST-MORTEM: three different phase-0 codings all cost +35 us vs the
// dense-key blend. The sort's lane-parallelism was already maximal (64
// pixels on 64 lanes) -- the cost is the FIXED phase-0 wall (~3000 cy of
// 1-wave VALU + memory RT) exposed on every one of 4096 blocks while 3
// waves idle at the barrier, at ~2.5 resident blocks/CU. Fix: AMORTIZE.
//   Phase 0: all 4 waves run the selection network CONCURRENTLY, one
//            64-pixel segment each (4 SIMDs busy; same wall, 4x output).
//            Writes s_idx DIRECTLY (idx = low32(key), -1 for SENT) --
//            s_key LDS and the phase-1 u64 decode are deleted.
//   Phase 1: 2048 entries over 256 threads: idx -> alpha (d2 from coords).
//   Phase 2: thread = pixel (256 active, was 64): cumprod + idx clamp.
//   Phase 3: per wave, 4 groups of 16 pixels: proven k-major gather loop.
//   Phase 4: transposed store per group (4x float4 = 64B line per lane).
// Barriers per pixel drop 4x; LDS 28.7 KB -> 5 blocks/CU.
// XCD-chunked swizzle kept (FETCH 49->32.5 MB in R5): 1024 = 8 x 128,
// logical = (blk&7)*128 + (blk>>3) -- each XCD owns 128 consecutive
// (b,h) rows. Perf heuristic only; correctness mapping-independent.
// LDS rows padded to K+1=9 (odd word stride -> conflict-free columns).
// ===========================================================================
__global__ __launch_bounds__(256) void blend_row_kernel(
        const float* __restrict__ pts,
        const float* __restrict__ feat,
        const unsigned int* __restrict__ counts,
        const unsigned long long* __restrict__ lists,
        float* __restrict__ out) {
    int blk = blockIdx.x;                        // 0..1023
    int logical = (blk & 7) * 128 + (blk >> 3);  // XCD chunk (1024 % 8 == 0)
    int h   = logical & 255;                     // image row
    int b   = logical >> 8;                      // batch
    int tid = threadIdx.x;
    int wave = tid >> 6;    // 0..3
    int lane = tid & 63;

    __shared__ float s_alpha[256][K + 1];
    __shared__ float s_wgt[256][K + 1];
    __shared__ int   s_idx[256][K + 1];
    __shared__ int   s_cnt[256];

    const float* pb = pts + (size_t)b * NPTS * 3;

    // Phase 0: wave w selects its 64-pixel segment; lane = pixel in segment.
    {
        int p = wave * 64 + lane;   // pixel (column) 0..255
        size_t base = (size_t)b * (S * S) + (size_t)h * S + (size_t)p;
        const ulonglong2* lp2 =
            reinterpret_cast<const ulonglong2*>(lists + base * (size_t)CAP);

        // all 11 loads independent -> single round-trip
        ulonglong2 q0 = lp2[0], q1 = lp2[1], q2 = lp2[2], q3 = lp2[3];
        ulonglong2 q4 = lp2[4], q5 = lp2[5], q6 = lp2[6], q7 = lp2[7];
        ulonglong2 q8 = lp2[8], q9 = lp2[9];
        int c = (int)counts[base];
        if (c > CAP) c = CAP;

        unsigned long long t0 = SENT, t1 = SENT, t2 = SENT, t3 = SENT;
        unsigned long long t4 = SENT, t5 = SENT, t6 = SENT, t7 = SENT;

        PAIR(0, q0); PAIR(1, q1); PAIR(2, q2); PAIR(3, q3); PAIR(4, q4);
        PAIR(5, q5); PAIR(6, q6); PAIR(7, q7); PAIR(8, q8); PAIR(9, q9);

        // direct idx write: low 32 bits of key; -1 marks empty slot
        s_idx[p][0] = (t0 == SENT) ? -1 : (int)(unsigned int)t0;
        s_idx[p][1] = (t1 == SENT) ? -1 : (int)(unsigned int)t1;
        s_idx[p][2] = (t2 == SENT) ? -1 : (int)(unsigned int)t2;
        s_idx[p][3] = (t3 == SENT) ? -1 : (int)(unsigned int)t3;
        s_idx[p][4] = (t4 == SENT) ? -1 : (int)(unsigned int)t4;
        s_idx[p][5] = (t5 == SENT) ? -1 : (int)(unsigned int)t5;
        s_idx[p][6] = (t6 == SENT) ? -1 : (int)(unsigned int)t6;
        s_idx[p][7] = (t7 == SENT) ? -1 : (int)(unsigned int)t7;
        s_cnt[p] = c < K ? c : K;
    }
    __syncthreads();

    // Phase 1: 2048 entries, 8 per thread: idx -> alpha
    float cyr = 1.0f - 2.0f * ((float)h + 0.5f) / 256.0f;
    for (int e = tid; e < 256 * K; e += 256) {
        int p = e >> 3;
        int k = e & 7;
        int idx = s_idx[p][k];
        float alpha = 0.0f;
        if (idx >= 0) {
            float x = -pb[(size_t)idx * 3 + 0];
            float y = -pb[(size_t)idx * 3 + 1];
            float cx = 1.0f - 2.0f * ((float)p + 0.5f) / 256.0f;
            float dy = cyr - y;
            float dx = cx - x;
            float d2 = dy * dy + dx * dx;
            float dist = d2 / R2;
            dist = fminf(fmaxf(dist, 0.001f), 1.0f);
            alpha = 1.0f - sqrtf(dist);     // gamma = 1 -> **0.5
        }
        s_alpha[p][k] = alpha;
    }
    __syncthreads();

    // Phase 2: per-pixel exclusive cumprod + idx clamp (thread = pixel)
    {
        int p = tid;
        float t = 1.0f;
#pragma unroll
        for (int k = 0; k < K; ++k) {
            float a = s_alpha[p][k];        // 0 for invalid slots
            s_wgt[p][k] = a * t;
            t *= (1.0f - a);
            int raw = s_idx[p][k];
            s_idx[p][k] = raw < 0 ? 0 : raw;   // clamp for safe gather
        }
    }
    __syncthreads();

    // Phase 3+4: each wave handles its 64 pixels as 4 groups of 16.
    // lane = channel; invalid slots gather clamped idx 0 (L1-resident row)
    // with weight 0 == reference f[clip(i,0)] * 0.
    const float* fbl = feat + (size_t)b * NPTS * CCH + lane;
    for (int g = 0; g < 4; ++g) {
        int pbase = wave * 64 + g * 16;

        int kmax = 0;
#pragma unroll
        for (int i = 0; i < 16; ++i) {
            int c = s_cnt[pbase + i];
            kmax = c > kmax ? c : kmax;
        }

        float acc[16];
#pragma unroll
        for (int i = 0; i < 16; ++i) acc[i] = 0.0f;

#pragma unroll 2
        for (int k = 0; k < kmax; ++k) {
            float v[16];
#pragma unroll
            for (int i = 0; i < 16; ++i) {
                int idx = s_idx[pbase + i][k];      // wave-uniform broadcast
                v[i] = fbl[(size_t)idx << 6];
            }
#pragma unroll
            for (int i = 0; i < 16; ++i) {
                acc[i] += s_wgt[pbase + i][k] * v[i];
            }
        }

        size_t obase = (((size_t)b * CCH + lane) * S + h) * S + (size_t)pbase;
        float4* o4 = (float4*)(out + obase);
#pragma unroll
        for (int q = 0; q < 4; ++q) {
            o4[q] = make_float4(acc[4 * q + 0], acc[4 * q + 1],
                                acc[4 * q + 2], acc[4 * q + 3]);
        }
    }
}

// ===========================================================================
// FALLBACK PATH (unchanged, proven): sorted atomicMin cascade into dense
// per-pixel key slots + original dense blend. Used only if ws_size is too
// small for the append lists.
// ===========================================================================
__global__ __launch_bounds__(256) void scatter_kernel(
        const float* __restrict__ pts,
        unsigned long long* __restrict__ keys) {
    int gid = blockIdx.x * blockDim.x + threadIdx.x;
    if (gid >= BATCH * NPTS * 16) return;
    int cell = gid & 15;
    int pid  = gid >> 4;
    int b = pid / NPTS;
    int n = pid - b * NPTS;

    const float* p = pts + (size_t)pid * 3;
    float x = -p[0];
    float y = -p[1];
    float z = p[2];
    if (!(z >= 0.0f)) return;

    float px = (1.0f - x) * 128.0f - 0.5f;
    float py = (1.0f - y) * 128.0f - 0.5f;
    int cj0 = (int)floorf(px);
    int ci0 = (int)floorf(py);

    int ci = ci0 - 1 + (cell >> 2);
    int cj = cj0 - 1 + (cell & 3);
    if (ci < 0 || ci >= S || cj < 0 || cj >= S) return;

    float cy = 1.0f - 2.0f * ((float)ci + 0.5f) / 256.0f;
    float cx = 1.0f - 2.0f * ((float)cj + 0.5f) / 256.0f;
    float dy = cy - y;
    float dx = cx - x;
    float d2 = dy * dy + dx * dx;
    if (!(d2 <= R2)) return;

    unsigned long long key =
        ((unsigned long long)__float_as_uint(z) << 32) | (unsigned int)n;
    unsigned long long* slot =
        keys + ((size_t)b * S * S + (size_t)(ci * S + cj)) * K;

    if (slot[K - 1] < key) return;

    for (int s = 0; s < K; ++s) {
        if (key == SENT) break;
        unsigned long long old = atomicMin(&slot[s], key);
        key = old > key ? old : key;
    }
}

__global__ __launch_bounds__(256) void blend_kernel(
        const float* __restrict__ pts,
        const float* __restrict__ feat,
        const unsigned long long* __restrict__ keys,
        float* __restrict__ out) {
    int seg = blockIdx.x;
    int h   = blockIdx.y;
    int b   = blockIdx.z;
    int tid = threadIdx.x;
    int w0  = seg * 64;

    __shared__ float s_alpha[64][K + 1];
    __shared__ float s_wgt[64][K + 1];
    __shared__ int   s_idx[64][K + 1];
    __shared__ int   s_cnt[64];

    const unsigned long long* kb =
        keys + ((size_t)b * S * S + (size_t)h * S + w0) * K;
    const float* pb = pts + (size_t)b * NPTS * 3;

    for (int e = tid; e < 64 * K; e += 256) {
        int p = e >> 3;
        int k = e & 7;
        unsigned long long key = kb[(size_t)p * K + k];
        float alpha = 0.0f;
        int idx = -1;
        if (key != SENT) {
            idx = (int)(unsigned int)(key & 0xFFFFFFFFULL);
            float x = -pb[(size_t)idx * 3 + 0];
            float y = -pb[(size_t)idx * 3 + 1];
            int w = w0 + p;
            float cy = 1.0f - 2.0f * ((float)h + 0.5f) / 256.0f;
            float cx = 1.0f - 2.0f * ((float)w + 0.5f) / 256.0f;
            float dy = cy - y;
            float dx = cx - x;
            float d2 = dy * dy + dx * dx;
            float dist = d2 / R2;
            dist = fminf(fmaxf(dist, 0.001f), 1.0f);
            alpha = 1.0f - sqrtf(dist);
        }
        s_alpha[p][k] = alpha;
        s_idx[p][k] = idx;
    }
    __syncthreads();

    if (tid < 64) {
        float t = 1.0f;
        int cnt = 0;
        for (int k = 0; k < K; ++k) {
            int raw = s_idx[tid][k];
            float a = s_alpha[tid][k];
            s_wgt[tid][k] = a * t;
            t *= (1.0f - a);
            if (raw >= 0) cnt = k + 1;
            s_idx[tid][k] = raw < 0 ? 0 : raw;
        }
        s_cnt[tid] = cnt;
    }
    __syncthreads();

    int wave = tid >> 6;
    int lane = tid & 63;
    int pbase = wave * 16;

    int kmax = 0;
#pragma unroll
    for (int i = 0; i < 16; ++i) {
        int c = s_cnt[pbase + i];
        kmax = c > kmax ? c : kmax;
    }

    float acc[16];
#pragma unroll
    for (int i = 0; i < 16; ++i) acc[i] = 0.0f;

    const float* fbl = feat + (size_t)b * NPTS * CCH + lane;
    for (int k = 0; k < kmax; ++k) {
        float v[16];
#pragma unroll
        for (int i = 0; i < 16; ++i) {
            int idx = s_idx[pbase + i][k];
            v[i] = fbl[(size_t)idx << 6];
        }
#pragma unroll
        for (int i = 0; i < 16; ++i) {
            acc[i] += s_wgt[pbase + i][k] * v[i];
        }
    }

    size_t obase = (((size_t)b * CCH + lane) * S + h) * S + (size_t)(w0 + pbase);
    float4* o4 = (float4*)(out + obase);
#pragma unroll
    for (int q = 0; q < 4; ++q) {
        o4[q] = make_float4(acc[4 * q + 0], acc[4 * q + 1],
                            acc[4 * q + 2], acc[4 * q + 3]);
    }
}

extern "C" void kernel_launch(void* const* d_in, const int* in_sizes, int n_in,
                              void* d_out, int out_size, void* d_ws, size_t ws_size,
                              hipStream_t stream) {
    const float* pts  = (const float*)d_in[0];
    const float* feat = (const float*)d_in[1];
    float* out = (float*)d_out;

    size_t cnt_bytes  = (size_t)BATCH * S * S * sizeof(unsigned int);      // 1 MB
    size_t list_bytes = (size_t)BATCH * S * S * CAP * sizeof(unsigned long long); // 42 MB
    size_t key_bytes  = (size_t)BATCH * S * S * K * sizeof(unsigned long long);   // 16.8 MB

    if (ws_size >= cnt_bytes + list_bytes) {
        // list path: 1-atomic scatter -> row-fused select+blend
        unsigned int* counts = (unsigned int*)d_ws;
        unsigned long long* lists =
            (unsigned long long*)((char*)d_ws + cnt_bytes);
        hipMemsetAsync(counts, 0, cnt_bytes, stream);

        int total = BATCH * NPTS * 16;
        scatter_list_kernel<<<(total + 255) / 256, 256, 0, stream>>>(
            pts, counts, lists);

        blend_row_kernel<<<BATCH * S, 256, 0, stream>>>(
            pts, feat, counts, lists, out);
    } else {
        // fallback: proven sorted-cascade path
        unsigned long long* keys = (unsigned long long*)d_ws;
        hipMemsetAsync(keys, 0xFF, key_bytes, stream);

        int total = BATCH * NPTS * 16;
        scatter_kernel<<<(total + 255) / 256, 256, 0, stream>>>(pts, keys);

        dim3 grid(S / 64, S, BATCH);
        blend_kernel<<<grid, 256, 0, stream>>>(pts, feat, keys, out);
    }
}

// Round 10
// 252.034 us; speedup vs baseline: 1.0233x; 1.0233x over previous
//
#include <hip/hip_runtime.h>
#include <stdint.h>

// Disable FP contraction file-wide: the d2 <= R2 inclusion test is a discrete
// decision that must match the reference's fp32 mul+add rounding (XLA/numpy do
// not fuse into fma across ops).
#pragma clang fp contract(off)

#define S 256
#define NPTS 100000
#define BATCH 4
#define CCH 64
#define K 8
#define CAP 20   // per-pixel candidate list capacity (lambda<=3.4, P(>20)~1e-10)

static constexpr float R2 = 0.01171875f * 0.01171875f;  // (1.5/256*2)^2, exact
static constexpr unsigned long long SENT = 0xFFFFFFFFFFFFFFFFULL;

// ===========================================================================
// Stage 1 -- Scatter: 16 THREADS PER POINT (one per 4x4 cell), append-list
// commit. PROVEN (R1; ~15 us standalone; R2's 1-thread/point regressed).
// NEW (R10): also stores ALPHA per candidate, computed here with the exact
// FP sequence blend previously used (same d2 value that passed the test,
// same clamp/sqrt ops -> bit-identical). This deletes blend's entire
// phase 1 (scattered pts re-gather + sqrt) and one barrier.
// key = (z_bits << 32) | point_idx -- ascending (z, idx) == reference
// lexsort rank; keys unique, so deferred selection reproduces the reference
// top-K exactly regardless of commit order.
// ===========================================================================
__global__ __launch_bounds__(256) void scatter_list_kernel(
        const float* __restrict__ pts,
        unsigned int* __restrict__ counts,
        unsigned long long* __restrict__ lists,
        float* __restrict__ lists_a) {
    int gid = blockIdx.x * blockDim.x + threadIdx.x;
    if (gid >= BATCH * NPTS * 16) return;
    int cell = gid & 15;
    int pid  = gid >> 4;
    int b = pid / NPTS;
    int n = pid - b * NPTS;

    const float* p = pts + (size_t)pid * 3;
    float x = -p[0];                 // reference flips x,y signs
    float y = -p[1];
    float z = p[2];
    if (!(z >= 0.0f)) return;

    float px = (1.0f - x) * 128.0f - 0.5f;   // (1-x)*(S/2) - 0.5
    float py = (1.0f - y) * 128.0f - 0.5f;
    int cj0 = (int)floorf(px);
    int ci0 = (int)floorf(py);

    int ci = ci0 - 1 + (cell >> 2);
    int cj = cj0 - 1 + (cell & 3);
    if (ci < 0 || ci >= S || cj < 0 || cj >= S) return;

    float cy = 1.0f - 2.0f * ((float)ci + 0.5f) / 256.0f;
    float cx = 1.0f - 2.0f * ((float)cj + 0.5f) / 256.0f;
    float dy = cy - y;
    float dx = cx - x;
    float d2 = dy * dy + dx * dx;
    if (!(d2 <= R2)) return;

    // alpha: exact ops blend used (same d2 -> identical bits)
    float dist = d2 / R2;
    dist = fminf(fmaxf(dist, 0.001f), 1.0f);
    float alpha = 1.0f - sqrtf(dist);        // gamma = 1 -> **0.5

    unsigned long long key =
        ((unsigned long long)__float_as_uint(z) << 32) | (unsigned int)n;
    size_t base = (size_t)b * (S * S) + (size_t)(ci * S + cj);
    unsigned int old = atomicAdd(&counts[base], 1u);
    if (old < CAP) {
        lists[base * CAP + old] = key;
        lists_a[base * CAP + old] = alpha;
    }
}

// payload compare-swap (ascending by key; alpha travels with its key) and
// sorted-insert for the streaming top-8. Inserting (SENT, 0) is a no-op,
// and the (SENT -> alpha 0) pairing is an invariant of the network, so
// invalid slots come out with weight-producing alpha exactly 0.
#define CSWP(ka, aa, kb, ab) do {                             \
        bool _lt = (ka) < (kb);                               \
        unsigned long long _kl = _lt ? (ka) : (kb);           \
        unsigned long long _kh = _lt ? (kb) : (ka);           \
        float _al = _lt ? (aa) : (ab);                        \
        float _ah = _lt ? (ab) : (aa);                        \
        (ka) = _kl; (kb) = _kh; (aa) = _al; (ab) = _ah;       \
    } while (0)
#define INS8P(e, kk, aa) do {                                             \
        unsigned long long _k = ((e) < c) ? (kk) : SENT;                  \
        float _a = ((e) < c) ? (aa) : 0.0f;                               \
        bool _r = _k < t7;                                                \
        t7 = _r ? _k : t7; a7 = _r ? _a : a7;                             \
        CSWP(t6, a6, t7, a7); CSWP(t5, a5, t6, a6);                       \
        CSWP(t4, a4, t5, a5); CSWP(t3, a3, t4, a4);                       \
        CSWP(t2, a2, t3, a3); CSWP(t1, a1, t2, a2);                       \
        CSWP(t0, a0, t1, a1);                                             \
    } while (0)

// ===========================================================================
// Stage 2 -- Blend. PROVEN R6 skeleton (4096 blocks, (b,h,64-px segment),
// XCD-chunked swizzle) with phases 1+2 DELETED:
//   R9 post-mortem: moving the selection (standalone kernel / 4-wave row /
//   1-wave segment) never helped -- so delete work instead. Alpha now
//   arrives precomputed from scatter; phase 0 sorts (key, alpha) pairs on
//   named registers, fuses the exclusive cumprod in-register (same thread
//   owns the pixel), and writes s_idx + s_wgt directly. One barrier total
//   (was three); no pts gather, no sqrt pass; LDS 11.7 -> ~4.9 KB.
//   Phase 3: unchanged proven k-major gather loop (lane = channel, 16
//   independent gathers in flight, invalid slots gather L1-resident row 0
//   with weight 0) + transposed 64B-line stores.
// Spill watch: all sort state in NAMED registers (q0..q9, f0..f4, t0..t7,
// a0..a7 ~ 95 VGPR live peak). Revert trigger: WRITE_SIZE +8 MB anomaly.
// ===========================================================================
__global__ __launch_bounds__(256) void blend_list_kernel(
        const float* __restrict__ feat,
        const unsigned int* __restrict__ counts,
        const unsigned long long* __restrict__ lists,
        const float* __restrict__ lists_a,
        float* __restrict__ out) {
    int blk = blockIdx.x;                       // 0..4095
    int logical = (blk & 7) * 512 + (blk >> 3); // XCD chunk (4096 % 8 == 0)
    int seg = logical & 3;                      // 0..3  (w segment)
    int h   = (logical >> 2) & 255;             // 0..255
    int b   = logical >> 10;                    // 0..3
    int tid = threadIdx.x;
    int w0  = seg * 64;

    __shared__ float s_wgt[64][K + 1];
    __shared__ int   s_idx[64][K + 1];
    __shared__ int   s_cnt[64];

    // Phase 0: wave 0, one pixel per lane: single-round-trip loads ->
    // payload selection network -> in-register cumprod -> LDS.
    if (tid < 64) {
        size_t base = (size_t)b * (S * S) + (size_t)h * S + (size_t)(w0 + tid);
        const ulonglong2* lp2 =
            reinterpret_cast<const ulonglong2*>(lists + base * (size_t)CAP);
        const float4* ap4 =
            reinterpret_cast<const float4*>(lists_a + base * (size_t)CAP);

        // all 16 loads independent -> single round-trip
        ulonglong2 q0 = lp2[0], q1 = lp2[1], q2 = lp2[2], q3 = lp2[3];
        ulonglong2 q4 = lp2[4], q5 = lp2[5], q6 = lp2[6], q7 = lp2[7];
        ulonglong2 q8 = lp2[8], q9 = lp2[9];
        float4 f0 = ap4[0], f1 = ap4[1], f2 = ap4[2], f3 = ap4[3], f4 = ap4[4];
        int c = (int)counts[base];
        if (c > CAP) c = CAP;

        unsigned long long t0 = SENT, t1 = SENT, t2 = SENT, t3 = SENT;
        unsigned long long t4 = SENT, t5 = SENT, t6 = SENT, t7 = SENT;
        float a0 = 0.0f, a1 = 0.0f, a2 = 0.0f, a3 = 0.0f;
        float a4 = 0.0f, a5 = 0.0f, a6 = 0.0f, a7 = 0.0f;

        INS8P(0,  q0.x, f0.x); INS8P(1,  q0.y, f0.y);
        INS8P(2,  q1.x, f0.z); INS8P(3,  q1.y, f0.w);
        INS8P(4,  q2.x, f1.x); INS8P(5,  q2.y, f1.y);
        INS8P(6,  q3.x, f1.z); INS8P(7,  q3.y, f1.w);
        INS8P(8,  q4.x, f2.x); INS8P(9,  q4.y, f2.y);
        INS8P(10, q5.x, f2.z); INS8P(11, q5.y, f2.w);
        INS8P(12, q6.x, f3.x); INS8P(13, q6.y, f3.y);
        INS8P(14, q7.x, f3.z); INS8P(15, q7.y, f3.w);
        INS8P(16, q8.x, f4.x); INS8P(17, q8.y, f4.y);
        INS8P(18, q9.x, f4.z); INS8P(19, q9.y, f4.w);

        // fused exclusive cumprod (reference: w = a * prod(1-a_prev));
        // invalid slots have alpha exactly 0 -> weight 0. idx clamped to 0
        // for safe gather (reference f[clip(i,0)] * 0).
        float t = 1.0f;
        s_wgt[tid][0] = a0 * t; t *= (1.0f - a0);
        s_wgt[tid][1] = a1 * t; t *= (1.0f - a1);
        s_wgt[tid][2] = a2 * t; t *= (1.0f - a2);
        s_wgt[tid][3] = a3 * t; t *= (1.0f - a3);
        s_wgt[tid][4] = a4 * t; t *= (1.0f - a4);
        s_wgt[tid][5] = a5 * t; t *= (1.0f - a5);
        s_wgt[tid][6] = a6 * t; t *= (1.0f - a6);
        s_wgt[tid][7] = a7 * t;
        s_idx[tid][0] = (t0 == SENT) ? 0 : (int)(unsigned int)t0;
        s_idx[tid][1] = (t1 == SENT) ? 0 : (int)(unsigned int)t1;
        s_idx[tid][2] = (t2 == SENT) ? 0 : (int)(unsigned int)t2;
        s_idx[tid][3] = (t3 == SENT) ? 0 : (int)(unsigned int)t3;
        s_idx[tid][4] = (t4 == SENT) ? 0 : (int)(unsigned int)t4;
        s_idx[tid][5] = (t5 == SENT) ? 0 : (int)(unsigned int)t5;
        s_idx[tid][6] = (t6 == SENT) ? 0 : (int)(unsigned int)t6;
        s_idx[tid][7] = (t7 == SENT) ? 0 : (int)(unsigned int)t7;
        s_cnt[tid] = c < K ? c : K;
    }
    __syncthreads();

    // Phase 3: k-major accumulate, 16 independent gathers per k, unroll 2.
    int wave = tid >> 6;    // 0..3
    int lane = tid & 63;    // channel
    int pbase = wave * 16;

    int kmax = 0;
#pragma unroll
    for (int i = 0; i < 16; ++i) {
        int c = s_cnt[pbase + i];
        kmax = c > kmax ? c : kmax;
    }

    float acc[16];
#pragma unroll
    for (int i = 0; i < 16; ++i) acc[i] = 0.0f;

    const float* fbl = feat + (size_t)b * NPTS * CCH + lane;
#pragma unroll 2
    for (int k = 0; k < kmax; ++k) {
        float v[16];
#pragma unroll
        for (int i = 0; i < 16; ++i) {
            int idx = s_idx[pbase + i][k];          // wave-uniform broadcast
            v[i] = fbl[(size_t)idx << 6];
        }
#pragma unroll
        for (int i = 0; i < 16; ++i) {
            acc[i] += s_wgt[pbase + i][k] * v[i];
        }
    }

    // Phase 4: transposed store, one 64B line per lane (4x float4)
    size_t obase = (((size_t)b * CCH + lane) * S + h) * S + (size_t)(w0 + pbase);
    float4* o4 = (float4*)(out + obase);
#pragma unroll
    for (int q = 0; q < 4; ++q) {
        o4[q] = make_float4(acc[4 * q + 0], acc[4 * q + 1],
                            acc[4 * q + 2], acc[4 * q + 3]);
    }
}

// ===========================================================================
// FALLBACK PATH (unchanged, proven): sorted atomicMin cascade into dense
// per-pixel key slots + original dense blend. Used only if ws_size is too
// small for the append lists.
// ===========================================================================
__global__ __launch_bounds__(256) void scatter_kernel(
        const float* __restrict__ pts,
        unsigned long long* __restrict__ keys) {
    int gid = blockIdx.x * blockDim.x + threadIdx.x;
    if (gid >= BATCH * NPTS * 16) return;
    int cell = gid & 15;
    int pid  = gid >> 4;
    int b = pid / NPTS;
    int n = pid - b * NPTS;

    const float* p = pts + (size_t)pid * 3;
    float x = -p[0];
    float y = -p[1];
    float z = p[2];
    if (!(z >= 0.0f)) return;

    float px = (1.0f - x) * 128.0f - 0.5f;
    float py = (1.0f - y) * 128.0f - 0.5f;
    int cj0 = (int)floorf(px);
    int ci0 = (int)floorf(py);

    int ci = ci0 - 1 + (cell >> 2);
    int cj = cj0 - 1 + (cell & 3);
    if (ci < 0 || ci >= S || cj < 0 || cj >= S) return;

    float cy = 1.0f - 2.0f * ((float)ci + 0.5f) / 256.0f;
    float cx = 1.0f - 2.0f * ((float)cj + 0.5f) / 256.0f;
    float dy = cy - y;
    float dx = cx - x;
    float d2 = dy * dy + dx * dx;
    if (!(d2 <= R2)) return;

    unsigned long long key =
        ((unsigned long long)__float_as_uint(z) << 32) | (unsigned int)n;
    unsigned long long* slot =
        keys + ((size_t)b * S * S + (size_t)(ci * S + cj)) * K;

    if (slot[K - 1] < key) return;

    for (int s = 0; s < K; ++s) {
        if (key == SENT) break;
        unsigned long long old = atomicMin(&slot[s], key);
        key = old > key ? old : key;
    }
}

__global__ __launch_bounds__(256) void blend_kernel(
        const float* __restrict__ pts,
        const float* __restrict__ feat,
        const unsigned long long* __restrict__ keys,
        float* __restrict__ out) {
    int seg = blockIdx.x;
    int h   = blockIdx.y;
    int b   = blockIdx.z;
    int tid = threadIdx.x;
    int w0  = seg * 64;

    __shared__ float s_alpha[64][K + 1];
    __shared__ float s_wgt[64][K + 1];
    __shared__ int   s_idx[64][K + 1];
    __shared__ int   s_cnt[64];

    const unsigned long long* kb =
        keys + ((size_t)b * S * S + (size_t)h * S + w0) * K;
    const float* pb = pts + (size_t)b * NPTS * 3;

    for (int e = tid; e < 64 * K; e += 256) {
        int p = e >> 3;
        int k = e & 7;
        unsigned long long key = kb[(size_t)p * K + k];
        float alpha = 0.0f;
        int idx = -1;
        if (key != SENT) {
            idx = (int)(unsigned int)(key & 0xFFFFFFFFULL);
            float x = -pb[(size_t)idx * 3 + 0];
            float y = -pb[(size_t)idx * 3 + 1];
            int w = w0 + p;
            float cy = 1.0f - 2.0f * ((float)h + 0.5f) / 256.0f;
            float cx = 1.0f - 2.0f * ((float)w + 0.5f) / 256.0f;
            float dy = cy - y;
            float dx = cx - x;
            float d2 = dy * dy + dx * dx;
            float dist = d2 / R2;
            dist = fminf(fmaxf(dist, 0.001f), 1.0f);
            alpha = 1.0f - sqrtf(dist);
        }
        s_alpha[p][k] = alpha;
        s_idx[p][k] = idx;
    }
    __syncthreads();

    if (tid < 64) {
        float t = 1.0f;
        int cnt = 0;
        for (int k = 0; k < K; ++k) {
            int raw = s_idx[tid][k];
            float a = s_alpha[tid][k];
            s_wgt[tid][k] = a * t;
            t *= (1.0f - a);
            if (raw >= 0) cnt = k + 1;
            s_idx[tid][k] = raw < 0 ? 0 : raw;
        }
        s_cnt[tid] = cnt;
    }
    __syncthreads();

    int wave = tid >> 6;
    int lane = tid & 63;
    int pbase = wave * 16;

    int kmax = 0;
#pragma unroll
    for (int i = 0; i < 16; ++i) {
        int c = s_cnt[pbase + i];
        kmax = c > kmax ? c : kmax;
    }

    float acc[16];
#pragma unroll
    for (int i = 0; i < 16; ++i) acc[i] = 0.0f;

    const float* fbl = feat + (size_t)b * NPTS * CCH + lane;
    for (int k = 0; k < kmax; ++k) {
        float v[16];
#pragma unroll
        for (int i = 0; i < 16; ++i) {
            int idx = s_idx[pbase + i][k];
            v[i] = fbl[(size_t)idx << 6];
        }
#pragma unroll
        for (int i = 0; i < 16; ++i) {
            acc[i] += s_wgt[pbase + i][k] * v[i];
        }
    }

    size_t obase = (((size_t)b * CCH + lane) * S + h) * S + (size_t)(w0 + pbase);
    float4* o4 = (float4*)(out + obase);
#pragma unroll
    for (int q = 0; q < 4; ++q) {
        o4[q] = make_float4(acc[4 * q + 0], acc[4 * q + 1],
                            acc[4 * q + 2], acc[4 * q + 3]);
    }
}

extern "C" void kernel_launch(void* const* d_in, const int* in_sizes, int n_in,
                              void* d_out, int out_size, void* d_ws, size_t ws_size,
                              hipStream_t stream) {
    const float* pts  = (const float*)d_in[0];
    const float* feat = (const float*)d_in[1];
    float* out = (float*)d_out;

    size_t cnt_bytes  = (size_t)BATCH * S * S * sizeof(unsigned int);      // 1 MB
    size_t list_bytes = (size_t)BATCH * S * S * CAP * sizeof(unsigned long long); // 42 MB
    size_t alpha_bytes = (size_t)BATCH * S * S * CAP * sizeof(float);      // 21 MB
    size_t key_bytes  = (size_t)BATCH * S * S * K * sizeof(unsigned long long);   // 16.8 MB

    if (ws_size >= cnt_bytes + list_bytes + alpha_bytes) {
        // list path: 1-atomic scatter (key + alpha) -> fused select+blend
        unsigned int* counts = (unsigned int*)d_ws;
        unsigned long long* lists =
            (unsigned long long*)((char*)d_ws + cnt_bytes);
        float* lists_a = (float*)((char*)d_ws + cnt_bytes + list_bytes);
        hipMemsetAsync(counts, 0, cnt_bytes, stream);

        int total = BATCH * NPTS * 16;
        scatter_list_kernel<<<(total + 255) / 256, 256, 0, stream>>>(
            pts, counts, lists, lists_a);

        blend_list_kernel<<<4096, 256, 0, stream>>>(
            feat, counts, lists, lists_a, out);
    } else {
        // fallback: proven sorted-cascade path
        unsigned long long* keys = (unsigned long long*)d_ws;
        hipMemsetAsync(keys, 0xFF, key_bytes, stream);

        int total = BATCH * NPTS * 16;
        scatter_kernel<<<(total + 255) / 256, 256, 0, stream>>>(pts, keys);

        dim3 grid(S / 64, S, BATCH);
        blend_kernel<<<grid, 256, 0, stream>>>(pts, feat, keys, out);
    }
}